// Round 8
// baseline (27.777 us; speedup 1.0000x reference)
//
#include <hip/hip_runtime.h>

#define B_ 32
#define X_ 128
#define Y_ 256
#define C_ 64
#define BDIM 256
#define NIT 4
#define NBLK (B_ * X_ / NIT)    /* 1024 blocks, 4 blocks/CU -> all resident */
#define MIN_VALF -4294967295.0f

// Insert v into descending sorted triple (m1 >= m2 >= m3), keeping top-3.
__device__ __forceinline__ void insert3(float& m1, float& m2, float& m3, float v) {
    float hi1 = fmaxf(m1, v);
    float lo1 = fminf(m1, v);
    m1 = hi1;
    float hi2 = fmaxf(m2, lo1);
    float lo2 = fminf(m2, lo1);
    m2 = hi2;
    m3 = fmaxf(m3, lo2);
}

// Issue 8 clamped row-loads (rows y0+4*(k0+k), clamped to ylen-1).
__device__ __forceinline__ void issue8(const float* __restrict__ base, int y0, int ylen,
                                       float4 (&buf)[8], int k0) {
    const int ymax = ylen - 1;
    #pragma unroll
    for (int k = 0; k < 8; ++k) {
        const int yr = y0 + 4 * (k0 + k);
        const int yc = (yr < ylen) ? yr : ymax;
        buf[k] = *reinterpret_cast<const float4*>(base + ((size_t)yc << 6));
    }
}

// Masked accumulate of 8 buffered rows.
__device__ __forceinline__ void consume8(int y0, int ylen, const float4 (&buf)[8], int k0,
                                         float (&m1)[4], float (&m2)[4], float (&m3)[4],
                                         float (&s)[4]) {
    #pragma unroll
    for (int k = 0; k < 8; ++k) {
        const bool live = (y0 + 4 * (k0 + k)) < ylen;
        float vv[4] = {buf[k].x, buf[k].y, buf[k].z, buf[k].w};
        #pragma unroll
        for (int j = 0; j < 4; ++j) {
            s[j] += live ? vv[j] : 0.0f;
            insert3(m1[j], m2[j], m3[j], live ? vv[j] : MIN_VALF);
        }
    }
}

// 1024 all-resident blocks x 4 items. Per item: 4 waves each own a 64-row
// y-chunk. Item state (xm, ylen) for all 4 items is computed once at block
// start; the 8+8 rolling load pipeline keeps memory issue continuous across
// item boundaries (consume bufA(i) -> refill bufA with item i+1's rows ->
// consume bufB(i) -> refill bufB). One __syncthreads per item via LDS
// double-buffering of the partials.
__global__ __launch_bounds__(BDIM, 4) void topk_pool_kernel(
    const float* __restrict__ inp,
    const float* __restrict__ xmask,
    const float* __restrict__ ymask,
    float* __restrict__ out)
{
    const int tid  = threadIdx.x;
    const int lane = tid & 63;
    const int wv   = tid >> 6;
    const int c0   = (lane & 15) << 2;
    const int yofs = lane >> 4;

    __shared__ float lds[2][4 * 16 * 16];

    // ---- block startup: all items' (w, xm, ylen) in one burst ----
    int   wA [NIT + 1];
    float xmA[NIT + 1];
    int   ylA[NIT + 1];
    float invA[NIT + 1];
    {
        float ys[NIT];
        #pragma unroll
        for (int i = 0; i < NIT; ++i) {
            const int g = blockIdx.x * NIT + i;
            const int w = (g * 1997) & (B_ * X_ - 1);   // bijective scatter
            wA[i] = w;
            const int b = w >> 7, x = w & (X_ - 1);
            xmA[i] = xmask[b * X_ + x];
            const float* ym = ymask + b * Y_;
            ys[i] = ym[lane] + ym[lane + 64] + ym[lane + 128] + ym[lane + 192];
        }
        #pragma unroll
        for (int i = 0; i < NIT; ++i) {
            float t = ys[i];
            #pragma unroll
            for (int off = 32; off > 0; off >>= 1) t += __shfl_xor(t, off);
            ylA[i]  = (int)(t + 0.5f);
            invA[i] = 1.0f / t;                          // ylen >= 4 per setup
        }
        wA[NIT] = 0; xmA[NIT] = 0.0f; ylA[NIT] = 64; invA[NIT] = 0.0f;  // pad
    }

    const int y0 = wv * 64 + yofs;
    float4 bufA[8], bufB[8];

    // prologue: item 0's loads
    {
        const bool l0 = (xmA[0] != 0.0f) && (wv * 64 < ylA[0]);
        const float* base0 = inp + ((size_t)wA[0] << 14) + c0;
        if (l0) {
            issue8(base0, y0, ylA[0], bufA, 0);
            issue8(base0, y0, ylA[0], bufB, 8);
        }
    }

    #pragma unroll
    for (int i = 0; i < NIT; ++i) {
        const bool alive  = (xmA[i] != 0.0f);
        const bool loads  = alive && (wv * 64 < ylA[i]);
        const bool loadsN = (i + 1 < NIT) && (xmA[i + 1] != 0.0f)
                            && (wv * 64 < ylA[i + 1]);
        const float* baseN = inp + ((size_t)wA[i + 1] << 14) + c0;

        float m1[4], m2[4], m3[4], s[4];
        #pragma unroll
        for (int j = 0; j < 4; ++j) {
            m1[j] = MIN_VALF; m2[j] = MIN_VALF; m3[j] = MIN_VALF; s[j] = 0.0f;
        }

        if (loads)  consume8(y0, ylA[i], bufA, 0, m1, m2, m3, s);
        if (loadsN) issue8(baseN, y0, ylA[i + 1], bufA, 0);
        if (loads)  consume8(y0, ylA[i], bufB, 8, m1, m2, m3, s);
        if (loadsN) issue8(baseN, y0, ylA[i + 1], bufB, 8);

        if (alive) {
            // In-wave merge of the 4 y-subgroups.
            #pragma unroll
            for (int step = 0; step < 2; ++step) {
                const int msk = 16 << step;
                #pragma unroll
                for (int j = 0; j < 4; ++j) {
                    float o1 = __shfl_xor(m1[j], msk);
                    float o2 = __shfl_xor(m2[j], msk);
                    float o3 = __shfl_xor(m3[j], msk);
                    float os = __shfl_xor(s[j],  msk);
                    s[j] += os;
                    insert3(m1[j], m2[j], m3[j], o1);
                    insert3(m1[j], m2[j], m3[j], o2);
                    insert3(m1[j], m2[j], m3[j], o3);
                }
            }
            if (yofs == 0) {
                float* dst = &lds[i & 1][(wv * 16 + (lane & 15)) * 16];
                *reinterpret_cast<float4*>(dst +  0) = make_float4(m1[0], m1[1], m1[2], m1[3]);
                *reinterpret_cast<float4*>(dst +  4) = make_float4(m2[0], m2[1], m2[2], m2[3]);
                *reinterpret_cast<float4*>(dst +  8) = make_float4(m3[0], m3[1], m3[2], m3[3]);
                *reinterpret_cast<float4*>(dst + 12) = make_float4(s[0],  s[1],  s[2],  s[3]);
            }
        }
        __syncthreads();

        if (wv == 0) {
            float* orow = out + (size_t)wA[i] * (3 * C_);
            if (!alive) {
                orow[lane]       = 0.0f;
                orow[64 + lane]  = 0.0f;
                orow[128 + lane] = 0.0f;
            } else {
                const int lg = lane >> 2, e = lane & 3;
                float M1 = MIN_VALF, M2 = MIN_VALF, M3 = MIN_VALF, S = 0.0f;
                #pragma unroll
                for (int q = 0; q < 4; ++q) {
                    const float* src = &lds[i & 1][(q * 16 + lg) * 16];
                    float a = src[e], bb = src[4 + e], c = src[8 + e], d = src[12 + e];
                    S += d;
                    insert3(M1, M2, M3, a);
                    insert3(M1, M2, M3, bb);
                    insert3(M1, M2, M3, c);
                }
                const float mean = S * invA[i];
                orow[lane]       = M1 * xmA[i];
                orow[64 + lane]  = ((ylA[i] >= 3) ? (M1 + M2 + M3) * (1.0f / 3.0f) : mean) * xmA[i];
                orow[128 + lane] = mean;     // mean_pool is NOT x-masked in ref
            }
        }
        // No second sync needed: lds[i&1] is next written at item i+2, which
        // every wave reaches only after passing sync(i+1), which wave 0
        // reaches only after finishing these reads.
    }
}

extern "C" void kernel_launch(void* const* d_in, const int* in_sizes, int n_in,
                              void* d_out, int out_size, void* d_ws, size_t ws_size,
                              hipStream_t stream) {
    const float* inp   = (const float*)d_in[0];
    const float* xmask = (const float*)d_in[1];
    const float* ymask = (const float*)d_in[2];
    float* out = (float*)d_out;

    topk_pool_kernel<<<NBLK, BDIM, 0, stream>>>(inp, xmask, ymask, out);
}